// Round 1
// baseline (1216.249 us; speedup 1.0000x reference)
//
#include <hip/hip_runtime.h>
#include <math.h>

#define Bsz 512
#define Tsz 512
#define Fin 32
#define Hd 64
#define G4 256
#define CHUNK 32
#define NCH (Tsz / CHUNK)

// broadcast a wave-uniform scalar from a literal lane via v_readlane_b32
__device__ __forceinline__ float rl(float v, int lane) {
    return __int_as_float(__builtin_amdgcn_readlane(__float_as_int(v), lane));
}

__device__ __forceinline__ float fsig(float x) {
    // stable: x<<0 -> e=inf -> 1/(1+inf)=0 (no NaN)
    return 1.0f / (1.0f + __expf(-x));
}

__device__ __forceinline__ float ftanh(float x) {
    // overflow-safe tanh via exp of non-positive argument
    float ax = fabsf(x);
    float e  = __expf(-2.0f * ax);
    float t  = (1.0f - e) / (1.0f + e);
    return copysignf(t, x);
}

// ---------------- Layer 0: x[B,T,32] -> h1[B,T,64] ----------------
// One block per batch row. Thread g (0..255) owns gate row g: Wih0[g,0:32] and
// Whh0[g,0:64] live in VGPRs; per step, x-row and h-vector are broadcast from
// one ds_read via v_readlane (1 readlane : 1 fma).
__global__ __launch_bounds__(256, 2)
void lstm_layer0(const float* __restrict__ x,
                 const float* __restrict__ Wih,
                 const float* __restrict__ Whh,
                 const float* __restrict__ bih,
                 const float* __restrict__ bhh,
                 float* __restrict__ h1out)
{
    __shared__ __align__(16) float xbuf[2][CHUNK * Fin]; // 2 x 4KB double-buffered x chunks
    __shared__ __align__(16) float hbuf[CHUNK * Hd];     // 8KB h-output staging per chunk
    __shared__ float h_lds[Hd];
    __shared__ float gates[G4];

    const int tid  = threadIdx.x;
    const int lane = tid & 63;
    const int b    = blockIdx.x;

    float wih[Fin];
#pragma unroll
    for (int k = 0; k < Fin; ++k) wih[k] = Wih[tid * Fin + k];
    float whh[Hd];
#pragma unroll
    for (int k = 0; k < Hd; ++k) whh[k] = Whh[tid * Hd + k];
    const float bias = bih[tid] + bhh[tid];
    const bool is_tanh_gate = (tid >= 2 * Hd) && (tid < 3 * Hd); // wave-uniform (gate g block)

    float c = 0.0f;
    if (tid < Hd) h_lds[tid] = 0.0f;

    const float4* xsrc = (const float4*)(x + (size_t)b * Tsz * Fin);
    ((float4*)xbuf[0])[tid] = xsrc[tid]; // chunk0: 256 float4 = 4KB
    __syncthreads();

    for (int ci = 0; ci < NCH; ++ci) {
        const int cur = ci & 1;
        if (ci + 1 < NCH) {
            ((float4*)xbuf[cur ^ 1])[tid] = xsrc[(ci + 1) * (CHUNK * Fin / 4) + tid];
        }
#pragma unroll 1
        for (int ct = 0; ct < CHUNK; ++ct) {
            float xv = xbuf[cur][ct * Fin + (lane & 31)]; // lane l holds x[t][l%32]
            float hv = h_lds[lane];                       // lane l holds h[l]
            float a0 = bias, a1 = 0.f, a2 = 0.f, a3 = 0.f;
#pragma unroll
            for (int k = 0; k < Fin; k += 4) {
                a0 += rl(xv, k + 0) * wih[k + 0];
                a1 += rl(xv, k + 1) * wih[k + 1];
                a2 += rl(xv, k + 2) * wih[k + 2];
                a3 += rl(xv, k + 3) * wih[k + 3];
            }
#pragma unroll
            for (int k = 0; k < Hd; k += 4) {
                a0 += rl(hv, k + 0) * whh[k + 0];
                a1 += rl(hv, k + 1) * whh[k + 1];
                a2 += rl(hv, k + 2) * whh[k + 2];
                a3 += rl(hv, k + 3) * whh[k + 3];
            }
            float acc = (a0 + a1) + (a2 + a3);
            // apply nonlinearity per-gate, pre-barrier (spreads transcendentals over all waves)
            gates[tid] = is_tanh_gate ? ftanh(acc) : fsig(acc);
            __syncthreads();
            if (tid < Hd) {
                float gi = gates[tid];
                float gf = gates[Hd + tid];
                float gg = gates[2 * Hd + tid];
                float go = gates[3 * Hd + tid];
                c = gf * c + gi * gg;
                float h = go * ftanh(c);
                h_lds[tid] = h;
                hbuf[ct * Hd + tid] = h;
            }
            __syncthreads();
        }
        // flush this chunk's h outputs, coalesced float4 (512 float4 = 2/thread)
        float4* dst = (float4*)(h1out + (size_t)b * Tsz * Hd + (size_t)ci * CHUNK * Hd);
        dst[tid]       = ((const float4*)hbuf)[tid];
        dst[tid + 256] = ((const float4*)hbuf)[tid + 256];
    }
}

// ------- Layer 1 + FC: h1[B,T,64] -> out[B] (only last h2 needed) -------
__global__ __launch_bounds__(256, 2)
void lstm_layer1_fc(const float* __restrict__ h1,
                    const float* __restrict__ Wih,
                    const float* __restrict__ Whh,
                    const float* __restrict__ bih,
                    const float* __restrict__ bhh,
                    const float* __restrict__ fcW,
                    const float* __restrict__ fcb,
                    float* __restrict__ out)
{
    __shared__ __align__(16) float xbuf[2][CHUNK * Hd]; // 2 x 8KB
    __shared__ float h_lds[Hd];
    __shared__ float gates[G4];

    const int tid  = threadIdx.x;
    const int lane = tid & 63;
    const int b    = blockIdx.x;

    float wih[Hd];
#pragma unroll
    for (int k = 0; k < Hd; ++k) wih[k] = Wih[tid * Hd + k];
    float whh[Hd];
#pragma unroll
    for (int k = 0; k < Hd; ++k) whh[k] = Whh[tid * Hd + k];
    const float bias = bih[tid] + bhh[tid];
    const bool is_tanh_gate = (tid >= 2 * Hd) && (tid < 3 * Hd);

    float c  = 0.0f;
    float hl = 0.0f;
    if (tid < Hd) h_lds[tid] = 0.0f;

    const float4* xsrc = (const float4*)(h1 + (size_t)b * Tsz * Hd);
    ((float4*)xbuf[0])[tid]       = xsrc[tid];        // 512 float4 = 8KB
    ((float4*)xbuf[0])[tid + 256] = xsrc[tid + 256];
    __syncthreads();

    for (int ci = 0; ci < NCH; ++ci) {
        const int cur = ci & 1;
        if (ci + 1 < NCH) {
            ((float4*)xbuf[cur ^ 1])[tid]       = xsrc[(ci + 1) * (CHUNK * Hd / 4) + tid];
            ((float4*)xbuf[cur ^ 1])[tid + 256] = xsrc[(ci + 1) * (CHUNK * Hd / 4) + tid + 256];
        }
#pragma unroll 1
        for (int ct = 0; ct < CHUNK; ++ct) {
            float xv = xbuf[cur][ct * Hd + lane]; // lane l holds h1[t][l]
            float hv = h_lds[lane];
            float a0 = bias, a1 = 0.f, a2 = 0.f, a3 = 0.f;
#pragma unroll
            for (int k = 0; k < Hd; k += 4) {
                a0 += rl(xv, k + 0) * wih[k + 0];
                a1 += rl(xv, k + 1) * wih[k + 1];
                a2 += rl(xv, k + 2) * wih[k + 2];
                a3 += rl(xv, k + 3) * wih[k + 3];
            }
#pragma unroll
            for (int k = 0; k < Hd; k += 4) {
                a0 += rl(hv, k + 0) * whh[k + 0];
                a1 += rl(hv, k + 1) * whh[k + 1];
                a2 += rl(hv, k + 2) * whh[k + 2];
                a3 += rl(hv, k + 3) * whh[k + 3];
            }
            float acc = (a0 + a1) + (a2 + a3);
            gates[tid] = is_tanh_gate ? ftanh(acc) : fsig(acc);
            __syncthreads();
            if (tid < Hd) {
                float gi = gates[tid];
                float gf = gates[Hd + tid];
                float gg = gates[2 * Hd + tid];
                float go = gates[3 * Hd + tid];
                c  = gf * c + gi * gg;
                hl = go * ftanh(c);
                h_lds[tid] = hl;
            }
            __syncthreads();
        }
    }
    // fused FC: out[b] = sum_j h2_last[j] * fcW[j] + fcb
    if (tid < Hd) {
        float p = hl * fcW[tid];
#pragma unroll
        for (int off = 32; off > 0; off >>= 1)
            p += __shfl_down(p, off);
        if (tid == 0) out[b] = p + fcb[0];
    }
}

extern "C" void kernel_launch(void* const* d_in, const int* in_sizes, int n_in,
                              void* d_out, int out_size, void* d_ws, size_t ws_size,
                              hipStream_t stream)
{
    const float* x    = (const float*)d_in[0];
    const float* Wih0 = (const float*)d_in[1];
    const float* Whh0 = (const float*)d_in[2];
    const float* bih0 = (const float*)d_in[3];
    const float* bhh0 = (const float*)d_in[4];
    const float* Wih1 = (const float*)d_in[5];
    const float* Whh1 = (const float*)d_in[6];
    const float* bih1 = (const float*)d_in[7];
    const float* bhh1 = (const float*)d_in[8];
    const float* fcW  = (const float*)d_in[9];
    const float* fcb  = (const float*)d_in[10];
    float* out = (float*)d_out;
    float* h1  = (float*)d_ws; // B*T*H fp32 = 64 MB scratch

    lstm_layer0<<<dim3(Bsz), dim3(256), 0, stream>>>(x, Wih0, Whh0, bih0, bhh0, h1);
    lstm_layer1_fc<<<dim3(Bsz), dim3(256), 0, stream>>>(h1, Wih1, Whh1, bih1, bhh1, fcW, fcb, out);
}

// Round 2
// 841.140 us; speedup vs baseline: 1.4460x; 1.4460x over previous
//
#include <hip/hip_runtime.h>
#include <math.h>

#define Bsz 512
#define Tsz 512
#define Fin 32
#define Hd 64
#define CHUNK 32
#define NCH (Tsz / CHUNK)

typedef float v2f __attribute__((ext_vector_type(2)));

__device__ __forceinline__ float fsig(float x) {
    return 1.0f / (1.0f + __expf(-x));
}
__device__ __forceinline__ float ftanh(float x) {
    float ax = fabsf(x);
    float e  = __expf(-2.0f * ax);
    float t  = (1.0f - e) / (1.0f + e);
    return copysignf(t, x);
}

// ---------------- Layer 0: x[B,T,32] -> h1[B,T,64] ----------------
// One block per batch row; thread g owns gate row g (weights in VGPR float4s).
// Broadcast of x-row / h-vector via same-address ds_read_b128 (free broadcast,
// LDS pipe — no VALU readlane). One barrier per step: gates cross waves via a
// parity-double-buffered stride-5 LDS buffer; each wave keeps a private h copy
// and redundantly computes the c-update.
__global__ __launch_bounds__(256, 2)
void lstm_layer0(const float* __restrict__ x,
                 const float4* __restrict__ Wih4,
                 const float4* __restrict__ Whh4,
                 const float* __restrict__ bih,
                 const float* __restrict__ bhh,
                 float* __restrict__ h1out)
{
    __shared__ __align__(16) float xbuf[2][CHUNK * Fin]; // 2 x 4KB
    __shared__ __align__(16) float hbuf[CHUNK * Hd];     // 8KB output staging
    __shared__ __align__(16) float hcopy[4][Hd];         // per-wave private h
    __shared__ float glds[2][Hd * 5];                    // gates, stride 5 (conflict-free)

    const int tid  = threadIdx.x;
    const int lane = tid & 63;
    const int wv   = tid >> 6;   // wave id == gate block (i,f,g,o)
    const int b    = blockIdx.x;

    float4 wih[8];
#pragma unroll
    for (int q = 0; q < 8; ++q) wih[q] = Wih4[tid * 8 + q];
    float4 whh[16];
#pragma unroll
    for (int q = 0; q < 16; ++q) whh[q] = Whh4[tid * 16 + q];
    const float bias = bih[tid] + bhh[tid];
    const bool is_tanh_gate = (wv == 2); // wave-uniform

    float c = 0.0f;
    hcopy[wv][lane] = 0.0f;

    const float4* xsrc = (const float4*)(x + (size_t)b * Tsz * Fin);
    ((float4*)xbuf[0])[tid] = xsrc[tid];
    __syncthreads();

    for (int ci = 0; ci < NCH; ++ci) {
        const int cur = ci & 1;
        if (ci + 1 < NCH)
            ((float4*)xbuf[cur ^ 1])[tid] = xsrc[(ci + 1) * (CHUNK * Fin / 4) + tid];
#pragma unroll 1
        for (int ct = 0; ct < CHUNK; ++ct) {
            const int t = ci * CHUNK + ct;
            const int p = t & 1;
            const float4* xrow = (const float4*)&xbuf[cur][ct * Fin]; // uniform addr -> broadcast
            const float4* hrow = (const float4*)&hcopy[wv][0];        // own copy, uniform addr

            v2f acc0 = {bias, 0.0f};
            v2f acc1 = {0.0f, 0.0f};
#pragma unroll
            for (int q = 0; q < 8; ++q) {
                float4 xv = xrow[q];
                v2f b0 = {xv.x, xv.y}, b1 = {xv.z, xv.w};
                v2f w0 = {wih[q].x, wih[q].y}, w1 = {wih[q].z, wih[q].w};
                acc0 = __builtin_elementwise_fma(b0, w0, acc0);
                acc1 = __builtin_elementwise_fma(b1, w1, acc1);
            }
#pragma unroll
            for (int q = 0; q < 16; ++q) {
                float4 hv = hrow[q];
                v2f b0 = {hv.x, hv.y}, b1 = {hv.z, hv.w};
                v2f w0 = {whh[q].x, whh[q].y}, w1 = {whh[q].z, whh[q].w};
                acc0 = __builtin_elementwise_fma(b0, w0, acc0);
                acc1 = __builtin_elementwise_fma(b1, w1, acc1);
            }
            float a = (acc0.x + acc0.y) + (acc1.x + acc1.y);
            glds[p][lane * 5 + wv] = is_tanh_gate ? ftanh(a) : fsig(a);
            __syncthreads();
            // every wave redundantly updates its private c/h (identical values)
            float gi = glds[p][lane * 5 + 0];
            float gf = glds[p][lane * 5 + 1];
            float gg = glds[p][lane * 5 + 2];
            float go = glds[p][lane * 5 + 3];
            c = gf * c + gi * gg;
            float h = go * ftanh(c);
            hcopy[wv][lane] = h;
            if (wv == 0) hbuf[ct * Hd + lane] = h;
        }
        __syncthreads(); // hbuf visible to all before flush
        float4* dst = (float4*)(h1out + (size_t)b * Tsz * Hd + (size_t)ci * CHUNK * Hd);
        dst[tid]       = ((const float4*)hbuf)[tid];
        dst[tid + 256] = ((const float4*)hbuf)[tid + 256];
    }
}

// ------- Layer 1 + FC: h1[B,T,64] -> out[B] -------
__global__ __launch_bounds__(256, 2)
void lstm_layer1_fc(const float* __restrict__ h1,
                    const float4* __restrict__ Wih4,
                    const float4* __restrict__ Whh4,
                    const float* __restrict__ bih,
                    const float* __restrict__ bhh,
                    const float* __restrict__ fcW,
                    const float* __restrict__ fcb,
                    float* __restrict__ out)
{
    __shared__ __align__(16) float xbuf[2][CHUNK * Hd]; // 2 x 8KB
    __shared__ __align__(16) float hcopy[4][Hd];
    __shared__ float glds[2][Hd * 5];

    const int tid  = threadIdx.x;
    const int lane = tid & 63;
    const int wv   = tid >> 6;
    const int b    = blockIdx.x;

    float4 wih[16];
#pragma unroll
    for (int q = 0; q < 16; ++q) wih[q] = Wih4[tid * 16 + q];
    float4 whh[16];
#pragma unroll
    for (int q = 0; q < 16; ++q) whh[q] = Whh4[tid * 16 + q];
    const float bias = bih[tid] + bhh[tid];
    const bool is_tanh_gate = (wv == 2);

    float c  = 0.0f;
    float hl = 0.0f;
    hcopy[wv][lane] = 0.0f;

    const float4* xsrc = (const float4*)(h1 + (size_t)b * Tsz * Hd);
    ((float4*)xbuf[0])[tid]       = xsrc[tid];
    ((float4*)xbuf[0])[tid + 256] = xsrc[tid + 256];
    __syncthreads();

    for (int ci = 0; ci < NCH; ++ci) {
        const int cur = ci & 1;
        if (ci + 1 < NCH) {
            ((float4*)xbuf[cur ^ 1])[tid]       = xsrc[(ci + 1) * (CHUNK * Hd / 4) + tid];
            ((float4*)xbuf[cur ^ 1])[tid + 256] = xsrc[(ci + 1) * (CHUNK * Hd / 4) + tid + 256];
        }
#pragma unroll 1
        for (int ct = 0; ct < CHUNK; ++ct) {
            const int t = ci * CHUNK + ct;
            const int p = t & 1;
            const float4* xrow = (const float4*)&xbuf[cur][ct * Hd];
            const float4* hrow = (const float4*)&hcopy[wv][0];

            v2f acc0 = {bias, 0.0f};
            v2f acc1 = {0.0f, 0.0f};
#pragma unroll
            for (int q = 0; q < 16; ++q) {
                float4 xv = xrow[q];
                v2f b0 = {xv.x, xv.y}, b1 = {xv.z, xv.w};
                v2f w0 = {wih[q].x, wih[q].y}, w1 = {wih[q].z, wih[q].w};
                acc0 = __builtin_elementwise_fma(b0, w0, acc0);
                acc1 = __builtin_elementwise_fma(b1, w1, acc1);
            }
#pragma unroll
            for (int q = 0; q < 16; ++q) {
                float4 hv = hrow[q];
                v2f b0 = {hv.x, hv.y}, b1 = {hv.z, hv.w};
                v2f w0 = {whh[q].x, whh[q].y}, w1 = {whh[q].z, whh[q].w};
                acc0 = __builtin_elementwise_fma(b0, w0, acc0);
                acc1 = __builtin_elementwise_fma(b1, w1, acc1);
            }
            float a = (acc0.x + acc0.y) + (acc1.x + acc1.y);
            glds[p][lane * 5 + wv] = is_tanh_gate ? ftanh(a) : fsig(a);
            __syncthreads();
            float gi = glds[p][lane * 5 + 0];
            float gf = glds[p][lane * 5 + 1];
            float gg = glds[p][lane * 5 + 2];
            float go = glds[p][lane * 5 + 3];
            c  = gf * c + gi * gg;
            hl = go * ftanh(c);
            hcopy[wv][lane] = hl;
        }
    }
    // fused FC on last h2 (wave 0 only; hl is replicated across waves)
    if (wv == 0) {
        float psum = hl * fcW[lane];
#pragma unroll
        for (int off = 32; off > 0; off >>= 1)
            psum += __shfl_down(psum, off);
        if (lane == 0) out[b] = psum + fcb[0];
    }
}

extern "C" void kernel_launch(void* const* d_in, const int* in_sizes, int n_in,
                              void* d_out, int out_size, void* d_ws, size_t ws_size,
                              hipStream_t stream)
{
    const float* x    = (const float*)d_in[0];
    const float* Wih0 = (const float*)d_in[1];
    const float* Whh0 = (const float*)d_in[2];
    const float* bih0 = (const float*)d_in[3];
    const float* bhh0 = (const float*)d_in[4];
    const float* Wih1 = (const float*)d_in[5];
    const float* Whh1 = (const float*)d_in[6];
    const float* bih1 = (const float*)d_in[7];
    const float* bhh1 = (const float*)d_in[8];
    const float* fcW  = (const float*)d_in[9];
    const float* fcb  = (const float*)d_in[10];
    float* out = (float*)d_out;
    float* h1  = (float*)d_ws; // B*T*H fp32 = 64 MB scratch

    lstm_layer0<<<dim3(Bsz), dim3(256), 0, stream>>>(
        x, (const float4*)Wih0, (const float4*)Whh0, bih0, bhh0, h1);
    lstm_layer1_fc<<<dim3(Bsz), dim3(256), 0, stream>>>(
        h1, (const float4*)Wih1, (const float4*)Whh1, bih1, bhh1, fcW, fcb, out);
}